// Round 1
// baseline (7578.091 us; speedup 1.0000x reference)
//
#include <hip/hip_runtime.h>

typedef unsigned short u16;
typedef __attribute__((ext_vector_type(8))) short short8;
typedef __attribute__((ext_vector_type(4))) float f32x4;

__device__ __forceinline__ float bf2f(u16 u) {
  union { float f; unsigned int i; } x; x.i = ((unsigned int)u) << 16; return x.f;
}
__device__ __forceinline__ u16 f2bf(float f) {
  union { float f; unsigned int i; } x; x.f = f;
  unsigned int r = x.i + 0x7FFFu + ((x.i >> 16) & 1u);
  return (u16)(r >> 16);
}
__device__ __forceinline__ float sigmf(float x) { return 1.f / (1.f + __expf(-x)); }
// tanh via exp, safe at +/-inf: x->+inf gives 1-2/inf = 1; x->-inf gives 1-2/1*? exp->0 -> -1
__device__ __forceinline__ float tanhfast(float x) { return 1.f - 2.f / (__expf(2.f * x) + 1.f); }

// ---------------------------------------------------------------------------
// elementwise fp32 -> bf16 convert
__global__ __launch_bounds__(256) void f2bf_kernel(const float* __restrict__ src,
                                                   u16* __restrict__ dst, int n) {
  int i = blockIdx.x * 256 + threadIdx.x;
  if (i < n) dst[i] = f2bf(src[i]);
}

// pack Wq|Wk|Wv -> [512][192] bf16, bq|bk|bv -> [192] fp32
__global__ __launch_bounds__(256) void pack_qkv_kernel(
    const float* __restrict__ Wq, const float* __restrict__ Wk, const float* __restrict__ Wv,
    const float* __restrict__ bq, const float* __restrict__ bk, const float* __restrict__ bv,
    u16* __restrict__ Wp, float* __restrict__ bp) {
  int i = blockIdx.x * 256 + threadIdx.x;
  if (i < 512 * 192) {
    int k = i / 192, r = i % 192, s = r >> 6, c = r & 63;
    const float* W = (s == 0) ? Wq : ((s == 1) ? Wk : Wv);
    Wp[i] = f2bf(W[k * 64 + c]);
  }
  if (i < 192) {
    int s = i >> 6, c = i & 63;
    bp[i] = ((s == 0) ? bq : ((s == 1) ? bk : bv))[c];
  }
}

// ---------------------------------------------------------------------------
// generic bf16 MFMA GEMM: C[M,N] = A[M,K] @ B[K,N] + bias, optional sigmoid.
// 64x64 tile, 256 threads (4 waves), BK=64, mfma_f32_16x16x32_bf16.
// A-frag: A[m=lane&15][k=quad*8+j]; B-frag: B[k=quad*8+j][n=lane&15];
// D: row=quad*4+r, col=lane&15   (verified layouts per guide §3)
__global__ __launch_bounds__(256) void gemm_bf16(
    const u16* __restrict__ A, const u16* __restrict__ B, const float* __restrict__ bias,
    float* __restrict__ Cf, u16* __restrict__ Cb, int M, int N, int K, int act) {
  __shared__ u16 As[64][72];  // stride 144B = 9*16 -> b128-aligned, 2-way bank (free)
  __shared__ u16 Bs[64][72];  // transposed: Bs[n][k]
  int tid = threadIdx.x;
  int tm = blockIdx.x * 64, tn = blockIdx.y * 64;
  int w = tid >> 6, L = tid & 63, m15 = L & 15, q = L >> 4;
  int lr = tid >> 3, lk = (tid & 7) * 8;

  f32x4 zero = {0.f, 0.f, 0.f, 0.f};
  f32x4 acc[4];
#pragma unroll
  for (int j = 0; j < 4; ++j) acc[j] = zero;

  for (int tk = 0; tk < K; tk += 64) {
#pragma unroll
    for (int rr = lr; rr < 64; rr += 32) {
      short8 v = *(const short8*)(A + (size_t)(tm + rr) * K + tk + lk);
      *(short8*)&As[rr][lk] = v;
    }
#pragma unroll
    for (int rr = lr; rr < 64; rr += 32) {
      short8 v = *(const short8*)(B + (size_t)(tk + rr) * N + tn + lk);
      const short* pv = (const short*)&v;
#pragma unroll
      for (int j = 0; j < 8; ++j) Bs[lk + j][rr] = (u16)pv[j];
    }
    __syncthreads();
#pragma unroll
    for (int ks = 0; ks < 2; ++ks) {
      int k0 = ks * 32 + q * 8;
      short8 a = *(const short8*)&As[w * 16 + m15][k0];
#pragma unroll
      for (int j = 0; j < 4; ++j) {
        short8 b = *(const short8*)&Bs[j * 16 + m15][k0];
        acc[j] = __builtin_amdgcn_mfma_f32_16x16x32_bf16(a, b, acc[j], 0, 0, 0);
      }
    }
    __syncthreads();
  }
#pragma unroll
  for (int j = 0; j < 4; ++j) {
    int col = tn + j * 16 + m15;
    float bia = bias ? bias[col] : 0.f;
#pragma unroll
    for (int r = 0; r < 4; ++r) {
      int row = tm + w * 16 + q * 4 + r;
      float v = acc[j][r] + bia;
      if (act == 1) v = sigmf(v);
      if (Cf) Cf[(size_t)row * N + col] = v;
      if (Cb) Cb[(size_t)row * N + col] = f2bf(v);
    }
  }
}

// ---------------------------------------------------------------------------
// Persistent LSTM scan. 64 workgroups x 256 threads. wg owns 8 hidden units
// (32 Wh columns: i|f|g|o x 8), cached in LDS as bf16 for all 512 steps.
// Per step: stage h (bf16,16KB) -> LDS, 2 waves do MFMA [16,512]x[512,32],
// epilogue (128 threads) applies gates, writes h (global bf16) + hs (fp32),
// then device-scope flag barrier on cnt[t].
__global__ __launch_bounds__(256) void lstm_kernel(
    const float* __restrict__ Wh,   // [512][2048] fp32
    const u16* __restrict__ xg,     // [8192][2048] bf16 (x@Wx + b)
    float* __restrict__ hs,         // [8192][512] fp32 out
    u16* __restrict__ h_buf,        // [16][512] bf16 (h exchange)
    int* __restrict__ cnt)          // [512] zeroed before launch
{
  __shared__ u16 whT[32][520];  // whT[n][k] = Wh[k][gate(n)*512 + u0 + (n&7)]
  __shared__ u16 hL[16][520];   // h[b][k] bf16
  __shared__ float gl[16][34];  // gate preactivations [b][n]

  int tid = threadIdx.x;
  int u0 = blockIdx.x * 8;
  int w = tid >> 6, L = tid & 63, m15 = L & 15, q = L >> 4;
  int b = tid >> 3, u = tid & 7;  // epilogue mapping (tid < 128)
  int srow = tid >> 4, scol = (tid & 15) * 32;

  // preload Wh slice (bf16) — read once from HBM
  for (int idx = tid; idx < 32 * 512; idx += 256) {
    int k = idx >> 5, n = idx & 31;
    int gate = n >> 3, uu = n & 7;
    whT[n][k] = f2bf(Wh[(size_t)k * 2048 + gate * 512 + u0 + uu]);
  }
  float c = 0.f;
  __syncthreads();

#pragma unroll 1
  for (int t = 0; t < 512; ++t) {
    // stage h_{t-1}
    if (t == 0) {
      short8 z = {0, 0, 0, 0, 0, 0, 0, 0};
#pragma unroll
      for (int j = 0; j < 4; ++j) *(short8*)&hL[srow][scol + j * 8] = z;
    } else {
#pragma unroll
      for (int j = 0; j < 4; ++j)
        *(short8*)&hL[srow][scol + j * 8] =
            *(const short8*)(h_buf + srow * 512 + scol + j * 8);
    }
    __syncthreads();

    if (w < 2) {
      f32x4 acc = {0.f, 0.f, 0.f, 0.f};
#pragma unroll
      for (int kt = 0; kt < 16; ++kt) {
        int k0 = kt * 32 + q * 8;
        short8 a = *(const short8*)&hL[m15][k0];
        short8 bb = *(const short8*)&whT[w * 16 + m15][k0];
        acc = __builtin_amdgcn_mfma_f32_16x16x32_bf16(a, bb, acc, 0, 0, 0);
      }
#pragma unroll
      for (int r = 0; r < 4; ++r) gl[q * 4 + r][w * 16 + m15] = acc[r];
    }
    __syncthreads();

    if (tid < 128) {
      size_t xrow = ((size_t)b * 512 + t) * 2048 + u0 + u;
      float gi = gl[b][u]      + bf2f(xg[xrow]);
      float gf = gl[b][8 + u]  + bf2f(xg[xrow + 512]);
      float gg = gl[b][16 + u] + bf2f(xg[xrow + 1024]);
      float go = gl[b][24 + u] + bf2f(xg[xrow + 1536]);
      float si = sigmf(gi), sf = sigmf(gf), tg = tanhfast(gg), so = sigmf(go);
      c = sf * c + si * tg;
      float h = so * tanhfast(c);
      h_buf[b * 512 + u0 + u] = f2bf(h);
      hs[((size_t)b * 512 + t) * 512 + u0 + u] = h;
    }

    // device-scope barrier: release our h writes, arrive, spin, acquire
    __threadfence();
    __syncthreads();
    if (tid == 0) {
      __hip_atomic_fetch_add(&cnt[t], 1, __ATOMIC_RELEASE, __HIP_MEMORY_SCOPE_AGENT);
      while (__hip_atomic_load(&cnt[t], __ATOMIC_ACQUIRE, __HIP_MEMORY_SCOPE_AGENT) < 64) {
        __builtin_amdgcn_s_sleep(2);
      }
    }
    __syncthreads();
    __threadfence();
  }
}

// ---------------------------------------------------------------------------
// LN1: y = LN(hs)*scale + bias + x ; writes fp32 + bf16. One wave per row.
__global__ __launch_bounds__(256) void ln1_kernel(
    const float* __restrict__ hsin, const float* __restrict__ x,
    const float* __restrict__ sc, const float* __restrict__ bi,
    float* __restrict__ hF, u16* __restrict__ hB) {
  int wv = threadIdx.x >> 6, ln = threadIdx.x & 63;
  size_t row = (size_t)blockIdx.x * 4 + wv;
  size_t rb = row * 512;
  float v[8];
  float s = 0.f;
#pragma unroll
  for (int j = 0; j < 8; ++j) { v[j] = hsin[rb + ln + j * 64]; s += v[j]; }
#pragma unroll
  for (int off = 32; off; off >>= 1) s += __shfl_xor(s, off);
  float mu = s * (1.f / 512.f);
  float vs = 0.f;
#pragma unroll
  for (int j = 0; j < 8; ++j) { float d = v[j] - mu; vs += d * d; }
#pragma unroll
  for (int off = 32; off; off >>= 1) vs += __shfl_xor(vs, off);
  float rs = rsqrtf(vs * (1.f / 512.f) + 1e-6f);
#pragma unroll
  for (int j = 0; j < 8; ++j) {
    int cc = ln + j * 64;
    float y = (v[j] - mu) * rs * sc[cc] + bi[cc] + x[rb + cc];
    hF[rb + cc] = y;
    hB[rb + cc] = f2bf(y);
  }
}

// LN2: out = LN(ao*gate + skip)*scale + bias
__global__ __launch_bounds__(256) void ln2_kernel(
    const float* __restrict__ ao, const float* __restrict__ gate,
    const float* __restrict__ skip, const float* __restrict__ sc,
    const float* __restrict__ bi, float* __restrict__ out) {
  int wv = threadIdx.x >> 6, ln = threadIdx.x & 63;
  size_t row = (size_t)blockIdx.x * 4 + wv;
  size_t rb = row * 512;
  float v[8];
  float s = 0.f;
#pragma unroll
  for (int j = 0; j < 8; ++j) {
    size_t ix = rb + ln + j * 64;
    v[j] = ao[ix] * gate[ix] + skip[ix];
    s += v[j];
  }
#pragma unroll
  for (int off = 32; off; off >>= 1) s += __shfl_xor(s, off);
  float mu = s * (1.f / 512.f);
  float vs = 0.f;
#pragma unroll
  for (int j = 0; j < 8; ++j) { float d = v[j] - mu; vs += d * d; }
#pragma unroll
  for (int off = 32; off; off >>= 1) vs += __shfl_xor(vs, off);
  float rs = rsqrtf(vs * (1.f / 512.f) + 1e-6f);
#pragma unroll
  for (int j = 0; j < 8; ++j) {
    int cc = ln + j * 64;
    out[rb + cc] = (v[j] - mu) * rs * sc[cc] + bi[cc];
  }
}

// ---------------------------------------------------------------------------
// attention: one wg per (b, head); 512 threads = 1 query each; K/V in LDS.
__global__ __launch_bounds__(512) void attn_kernel(const float* __restrict__ qkv,
                                                   u16* __restrict__ ctx) {
  __shared__ float4 kL[512][2];
  __shared__ float4 vL[512][2];
  int tid = threadIdx.x;
  int b = blockIdx.x >> 3, hd = blockIdx.x & 7;
  size_t base = ((size_t)b * 512 + tid) * 192;
  kL[tid][0] = *(const float4*)(qkv + base + 64 + hd * 8);
  kL[tid][1] = *(const float4*)(qkv + base + 64 + hd * 8 + 4);
  vL[tid][0] = *(const float4*)(qkv + base + 128 + hd * 8);
  vL[tid][1] = *(const float4*)(qkv + base + 128 + hd * 8 + 4);
  float4 qa = *(const float4*)(qkv + base + hd * 8);
  float4 qb = *(const float4*)(qkv + base + hd * 8 + 4);
  const float scl = 0.35355339059327373f;  // 1/sqrt(8)
  float q0 = qa.x * scl, q1 = qa.y * scl, q2 = qa.z * scl, q3 = qa.w * scl;
  float q4 = qb.x * scl, q5 = qb.y * scl, q6 = qb.z * scl, q7 = qb.w * scl;
  __syncthreads();
  float m = -1e30f, l = 0.f;
  float a0 = 0, a1 = 0, a2 = 0, a3 = 0, a4 = 0, a5 = 0, a6 = 0, a7 = 0;
  for (int t2 = 0; t2 < 512; ++t2) {
    float4 ka = kL[t2][0], kb = kL[t2][1];
    float s = q0 * ka.x + q1 * ka.y + q2 * ka.z + q3 * ka.w +
              q4 * kb.x + q5 * kb.y + q6 * kb.z + q7 * kb.w;
    float nm = fmaxf(m, s);
    float cor = __expf(m - nm);
    float e = __expf(s - nm);
    float4 va = vL[t2][0], vb = vL[t2][1];
    l = l * cor + e;
    a0 = a0 * cor + e * va.x; a1 = a1 * cor + e * va.y;
    a2 = a2 * cor + e * va.z; a3 = a3 * cor + e * va.w;
    a4 = a4 * cor + e * vb.x; a5 = a5 * cor + e * vb.y;
    a6 = a6 * cor + e * vb.z; a7 = a7 * cor + e * vb.w;
    m = nm;
  }
  float inv = 1.f / l;
  short8 o;
  o[0] = (short)f2bf(a0 * inv); o[1] = (short)f2bf(a1 * inv);
  o[2] = (short)f2bf(a2 * inv); o[3] = (short)f2bf(a3 * inv);
  o[4] = (short)f2bf(a4 * inv); o[5] = (short)f2bf(a5 * inv);
  o[6] = (short)f2bf(a6 * inv); o[7] = (short)f2bf(a7 * inv);
  *(short8*)(ctx + ((size_t)b * 512 + tid) * 64 + hd * 8) = o;
}

// ---------------------------------------------------------------------------
extern "C" void kernel_launch(void* const* d_in, const int* in_sizes, int n_in,
                              void* d_out, int out_size, void* d_ws, size_t ws_size,
                              hipStream_t stream) {
  (void)in_sizes; (void)n_in; (void)out_size; (void)ws_size;
  const float* x    = (const float*)d_in[0];
  const float* Wx   = (const float*)d_in[1];
  const float* Wh   = (const float*)d_in[2];
  const float* bls  = (const float*)d_in[3];
  const float* ln1s = (const float*)d_in[4];
  const float* ln1b = (const float*)d_in[5];
  const float* Wq   = (const float*)d_in[6];
  const float* bq   = (const float*)d_in[7];
  const float* Wk   = (const float*)d_in[8];
  const float* bk   = (const float*)d_in[9];
  const float* Wv   = (const float*)d_in[10];
  const float* bv   = (const float*)d_in[11];
  const float* Wo   = (const float*)d_in[12];
  const float* bo   = (const float*)d_in[13];
  const float* Wg   = (const float*)d_in[14];
  const float* bg   = (const float*)d_in[15];
  const float* ln2s = (const float*)d_in[16];
  const float* ln2b = (const float*)d_in[17];
  float* out = (float*)d_out;

  char* p = (char*)d_ws;
  auto alloc = [&](size_t bytes) -> char* {
    char* r = p;
    p += (bytes + 255) & ~(size_t)255;
    return r;
  };
  int* cnt      = (int*)alloc(512 * 4);
  u16* h_buf    = (u16*)alloc(16 * 512 * 2);
  u16* x_bf     = (u16*)alloc((size_t)8192 * 512 * 2);
  u16* Wx_bf    = (u16*)alloc((size_t)512 * 2048 * 2);
  u16* Wqkv_bf  = (u16*)alloc((size_t)512 * 192 * 2);
  float* bqkv   = (float*)alloc(192 * 4);
  u16* Wg_bf    = (u16*)alloc((size_t)512 * 512 * 2);
  u16* Wo_bf    = (u16*)alloc((size_t)64 * 512 * 2);
  u16* xg_bf    = (u16*)alloc((size_t)8192 * 2048 * 2);
  float* hs     = (float*)alloc((size_t)8192 * 512 * 4);
  float* hF     = (float*)alloc((size_t)8192 * 512 * 4);
  u16* hB       = (u16*)alloc((size_t)8192 * 512 * 2);
  float* qkvb   = (float*)alloc((size_t)8192 * 192 * 4);
  float* gatep  = (float*)alloc((size_t)8192 * 512 * 4);
  u16* ctx      = (u16*)alloc((size_t)8192 * 64 * 2);
  float* ao     = (float*)alloc((size_t)8192 * 512 * 4);

  hipMemsetAsync(cnt, 0, 512 * 4, stream);
  f2bf_kernel<<<16384, 256, 0, stream>>>(x, x_bf, 8192 * 512);
  f2bf_kernel<<<4096, 256, 0, stream>>>(Wx, Wx_bf, 512 * 2048);
  f2bf_kernel<<<1024, 256, 0, stream>>>(Wg, Wg_bf, 512 * 512);
  f2bf_kernel<<<128, 256, 0, stream>>>(Wo, Wo_bf, 64 * 512);
  pack_qkv_kernel<<<384, 256, 0, stream>>>(Wq, Wk, Wv, bq, bk, bv, Wqkv_bf, bqkv);

  // xg = x @ Wx + b  -> bf16 [8192,2048]
  gemm_bf16<<<dim3(128, 32), 256, 0, stream>>>(x_bf, Wx_bf, bls, nullptr, xg_bf,
                                               8192, 2048, 512, 0);
  // LSTM scan -> hs fp32 [8192,512]
  lstm_kernel<<<64, 256, 0, stream>>>(Wh, xg_bf, hs, h_buf, cnt);
  // h = LN(hs)+x  -> hF fp32, hB bf16
  ln1_kernel<<<2048, 256, 0, stream>>>(hs, x, ln1s, ln1b, hF, hB);
  // qkv = h @ [Wq|Wk|Wv] + b  -> fp32 [8192,192]
  gemm_bf16<<<dim3(128, 3), 256, 0, stream>>>(hB, Wqkv_bf, bqkv, qkvb, nullptr,
                                              8192, 192, 512, 0);
  // gate = sigmoid(h @ Wg + bg)  -> fp32 [8192,512]
  gemm_bf16<<<dim3(128, 8), 256, 0, stream>>>(hB, Wg_bf, bg, gatep, nullptr,
                                              8192, 512, 512, 1);
  // attention -> ctx bf16 [8192,64]
  attn_kernel<<<128, 512, 0, stream>>>(qkvb, ctx);
  // attn_out = ctx @ Wo + bo -> fp32 [8192,512]
  gemm_bf16<<<dim3(128, 8), 256, 0, stream>>>(ctx, Wo_bf, bo, ao, nullptr,
                                              8192, 512, 64, 0);
  // out = LN(ao*gate + h)
  ln2_kernel<<<2048, 256, 0, stream>>>(ao, gatep, hF, ln2s, ln2b, out);
}

// Round 2
// 2638.835 us; speedup vs baseline: 2.8718x; 2.8718x over previous
//
#include <hip/hip_runtime.h>

typedef unsigned short u16;
typedef __attribute__((ext_vector_type(8))) short short8;
typedef __attribute__((ext_vector_type(4))) float f32x4;

__device__ __forceinline__ float bf2f(u16 u) {
  union { float f; unsigned int i; } x; x.i = ((unsigned int)u) << 16; return x.f;
}
__device__ __forceinline__ u16 f2bf(float f) {
  union { float f; unsigned int i; } x; x.f = f;
  unsigned int r = x.i + 0x7FFFu + ((x.i >> 16) & 1u);
  return (u16)(r >> 16);
}
__device__ __forceinline__ float sigmf(float x) { return 1.f / (1.f + __expf(-x)); }
__device__ __forceinline__ float tanhfast(float x) { return 1.f - 2.f / (__expf(2.f * x) + 1.f); }

// ---------------------------------------------------------------------------
// elementwise fp32 -> bf16 convert
__global__ __launch_bounds__(256) void f2bf_kernel(const float* __restrict__ src,
                                                   u16* __restrict__ dst, int n) {
  int i = blockIdx.x * 256 + threadIdx.x;
  if (i < n) dst[i] = f2bf(src[i]);
}

// pack Wq|Wk|Wv -> [512][192] bf16, bq|bk|bv -> [192] fp32
__global__ __launch_bounds__(256) void pack_qkv_kernel(
    const float* __restrict__ Wq, const float* __restrict__ Wk, const float* __restrict__ Wv,
    const float* __restrict__ bq, const float* __restrict__ bk, const float* __restrict__ bv,
    u16* __restrict__ Wp, float* __restrict__ bp) {
  int i = blockIdx.x * 256 + threadIdx.x;
  if (i < 512 * 192) {
    int k = i / 192, r = i % 192, s = r >> 6, c = r & 63;
    const float* W = (s == 0) ? Wq : ((s == 1) ? Wk : Wv);
    Wp[i] = f2bf(W[k * 64 + c]);
  }
  if (i < 192) {
    int s = i >> 6, c = i & 63;
    bp[i] = ((s == 0) ? bq : ((s == 1) ? bk : bv))[c];
  }
}

// ---------------------------------------------------------------------------
// generic bf16 MFMA GEMM: C[M,N] = A[M,K] @ B[K,N] + bias, optional sigmoid.
// 64x64 tile, 256 threads (4 waves), BK=64, mfma_f32_16x16x32_bf16.
__global__ __launch_bounds__(256) void gemm_bf16(
    const u16* __restrict__ A, const u16* __restrict__ B, const float* __restrict__ bias,
    float* __restrict__ Cf, u16* __restrict__ Cb, int M, int N, int K, int act) {
  __shared__ u16 As[64][72];
  __shared__ u16 Bs[64][72];  // transposed: Bs[n][k]
  int tid = threadIdx.x;
  int tm = blockIdx.x * 64, tn = blockIdx.y * 64;
  int w = tid >> 6, L = tid & 63, m15 = L & 15, q = L >> 4;
  int lr = tid >> 3, lk = (tid & 7) * 8;

  f32x4 zero = {0.f, 0.f, 0.f, 0.f};
  f32x4 acc[4];
#pragma unroll
  for (int j = 0; j < 4; ++j) acc[j] = zero;

  for (int tk = 0; tk < K; tk += 64) {
#pragma unroll
    for (int rr = lr; rr < 64; rr += 32) {
      short8 v = *(const short8*)(A + (size_t)(tm + rr) * K + tk + lk);
      *(short8*)&As[rr][lk] = v;
    }
#pragma unroll
    for (int rr = lr; rr < 64; rr += 32) {
      short8 v = *(const short8*)(B + (size_t)(tk + rr) * N + tn + lk);
      const short* pv = (const short*)&v;
#pragma unroll
      for (int j = 0; j < 8; ++j) Bs[lk + j][rr] = (u16)pv[j];
    }
    __syncthreads();
#pragma unroll
    for (int ks = 0; ks < 2; ++ks) {
      int k0 = ks * 32 + q * 8;
      short8 a = *(const short8*)&As[w * 16 + m15][k0];
#pragma unroll
      for (int j = 0; j < 4; ++j) {
        short8 b = *(const short8*)&Bs[j * 16 + m15][k0];
        acc[j] = __builtin_amdgcn_mfma_f32_16x16x32_bf16(a, b, acc[j], 0, 0, 0);
      }
    }
    __syncthreads();
  }
#pragma unroll
  for (int j = 0; j < 4; ++j) {
    int col = tn + j * 16 + m15;
    float bia = bias ? bias[col] : 0.f;
#pragma unroll
    for (int r = 0; r < 4; ++r) {
      int row = tm + w * 16 + q * 4 + r;
      float v = acc[j][r] + bia;
      if (act == 1) v = sigmf(v);
      if (Cf) Cf[(size_t)row * N + col] = v;
      if (Cb) Cb[(size_t)row * N + col] = f2bf(v);
    }
  }
}

// ---------------------------------------------------------------------------
// Persistent LSTM scan. 64 wgs x 256 threads; wg owns 8 hidden units.
// All cross-wg traffic via device-scope RELAXED atomics (sc-bit loads/stores
// straight to the coherence point) — NO __threadfence, NO acquire spin loads,
// so no buffer_wbl2 / buffer_inv cache-wide ops in the step loop.
// Flag protocol: h stores (relaxed agent) -> __syncthreads (drains vmcnt) ->
// flags[wg]=t+1 (relaxed agent) -> wave0 lanes poll flags[lane] relaxed.
__global__ __launch_bounds__(256) void lstm_kernel(
    const float* __restrict__ Wh,          // [512][2048] fp32
    const u16* __restrict__ xg,            // [8192][2048] bf16 (x@Wx + b)
    float* __restrict__ hs,                // [8192][512] fp32 out
    unsigned int* __restrict__ h_buf32,    // [16*256] u32 (bf16 pairs)
    int* __restrict__ flags)               // [64] zeroed before launch
{
  __shared__ u16 whT[32][520];  // whT[n][k] = Wh[k][gate(n)*512 + u0 + (n&7)]
  __shared__ u16 hL[16][520];   // h[b][k] bf16
  __shared__ float gl[16][34];  // gate preactivations [b][n]

  int tid = threadIdx.x;
  int u0 = blockIdx.x * 8;
  int w = tid >> 6, L = tid & 63, m15 = L & 15, q = L >> 4;
  int b = tid >> 3, u = tid & 7;          // epilogue mapping (tid < 128)
  int srow = tid >> 4, sidx = tid & 15;   // staging mapping

  // preload Wh slice (bf16) — read once from HBM
  for (int idx = tid; idx < 32 * 512; idx += 256) {
    int k = idx >> 5, n = idx & 31;
    int gate = n >> 3, uu = n & 7;
    whT[n][k] = f2bf(Wh[(size_t)k * 2048 + gate * 512 + u0 + uu]);
  }
  float c = 0.f;
  __syncthreads();

  const unsigned long long* h_buf64 = (const unsigned long long*)h_buf32;

#pragma unroll 1
  for (int t = 0; t < 512; ++t) {
    // prefetch this step's xg early (consumed in epilogue, ~2 barriers later)
    float xi = 0.f, xf = 0.f, xgg = 0.f, xo = 0.f;
    if (tid < 128) {
      size_t xrow = ((size_t)b * 512 + t) * 2048 + u0 + u;
      xi  = bf2f(xg[xrow]);
      xf  = bf2f(xg[xrow + 512]);
      xgg = bf2f(xg[xrow + 1024]);
      xo  = bf2f(xg[xrow + 1536]);
    }

    // stage h_{t-1} -> LDS (device-scope relaxed u64 loads: always coherent)
    if (t == 0) {
      short8 z = {0, 0, 0, 0, 0, 0, 0, 0};
#pragma unroll
      for (int j = 0; j < 4; ++j) *(short8*)&hL[srow][sidx * 32 + j * 8] = z;
    } else {
#pragma unroll
      for (int jj = 0; jj < 8; ++jj) {
        unsigned long long v = __hip_atomic_load(
            &h_buf64[srow * 128 + sidx * 8 + jj],
            __ATOMIC_RELAXED, __HIP_MEMORY_SCOPE_AGENT);
        *(unsigned long long*)&hL[srow][(sidx * 8 + jj) * 4] = v;
      }
    }
    __syncthreads();

    if (w < 2) {
      f32x4 acc = {0.f, 0.f, 0.f, 0.f};
#pragma unroll
      for (int kt = 0; kt < 16; ++kt) {
        int k0 = kt * 32 + q * 8;
        short8 a = *(const short8*)&hL[m15][k0];
        short8 bb = *(const short8*)&whT[w * 16 + m15][k0];
        acc = __builtin_amdgcn_mfma_f32_16x16x32_bf16(a, bb, acc, 0, 0, 0);
      }
#pragma unroll
      for (int r = 0; r < 4; ++r) gl[q * 4 + r][w * 16 + m15] = acc[r];
    }
    __syncthreads();

    unsigned int hp = 0;
    if (tid < 128) {
      float gi = gl[b][u]      + xi;
      float gf = gl[b][8 + u]  + xf;
      float gg = gl[b][16 + u] + xgg;
      float go = gl[b][24 + u] + xo;
      float si = sigmf(gi), sf = sigmf(gf), tg = tanhfast(gg), so = sigmf(go);
      c = sf * c + si * tg;
      float h = so * tanhfast(c);
      hs[((size_t)b * 512 + t) * 512 + u0 + u] = h;
      hp = (unsigned int)f2bf(h);
    }
    // pack bf16 pair via lane^1 shuffle; even-u threads store u32
    unsigned int hot = (unsigned int)__shfl_xor((int)hp, 1);
    if (tid < 128 && (u & 1) == 0) {
      unsigned int pv = hp | (hot << 16);
      __hip_atomic_store(&h_buf32[b * 256 + (u0 >> 1) + (u >> 1)], pv,
                         __ATOMIC_RELAXED, __HIP_MEMORY_SCOPE_AGENT);
    }
    __syncthreads();  // drains vmcnt for ALL waves' h stores before flag

    int target = t + 1;
    if (tid == 0)
      __hip_atomic_store(&flags[blockIdx.x], target,
                         __ATOMIC_RELAXED, __HIP_MEMORY_SCOPE_AGENT);
    if (w == 0) {
      // each lane polls one wg's flag; wave exits when all 64 lanes see t+1
      while (__hip_atomic_load(&flags[L], __ATOMIC_RELAXED,
                               __HIP_MEMORY_SCOPE_AGENT) < target) {
        __builtin_amdgcn_s_sleep(1);
      }
    }
    __atomic_signal_fence(__ATOMIC_ACQ_REL);  // compiler ordering only
    __syncthreads();
  }
}

// ---------------------------------------------------------------------------
// LN1: y = LN(hs)*scale + bias + x ; writes fp32 + bf16. One wave per row.
__global__ __launch_bounds__(256) void ln1_kernel(
    const float* __restrict__ hsin, const float* __restrict__ x,
    const float* __restrict__ sc, const float* __restrict__ bi,
    float* __restrict__ hF, u16* __restrict__ hB) {
  int wv = threadIdx.x >> 6, ln = threadIdx.x & 63;
  size_t row = (size_t)blockIdx.x * 4 + wv;
  size_t rb = row * 512;
  float v[8];
  float s = 0.f;
#pragma unroll
  for (int j = 0; j < 8; ++j) { v[j] = hsin[rb + ln + j * 64]; s += v[j]; }
#pragma unroll
  for (int off = 32; off; off >>= 1) s += __shfl_xor(s, off);
  float mu = s * (1.f / 512.f);
  float vs = 0.f;
#pragma unroll
  for (int j = 0; j < 8; ++j) { float d = v[j] - mu; vs += d * d; }
#pragma unroll
  for (int off = 32; off; off >>= 1) vs += __shfl_xor(vs, off);
  float rs = rsqrtf(vs * (1.f / 512.f) + 1e-6f);
#pragma unroll
  for (int j = 0; j < 8; ++j) {
    int cc = ln + j * 64;
    float y = (v[j] - mu) * rs * sc[cc] + bi[cc] + x[rb + cc];
    hF[rb + cc] = y;
    hB[rb + cc] = f2bf(y);
  }
}

// LN2: out = LN(ao*gate + skip)*scale + bias
__global__ __launch_bounds__(256) void ln2_kernel(
    const float* __restrict__ ao, const float* __restrict__ gate,
    const float* __restrict__ skip, const float* __restrict__ sc,
    const float* __restrict__ bi, float* __restrict__ out) {
  int wv = threadIdx.x >> 6, ln = threadIdx.x & 63;
  size_t row = (size_t)blockIdx.x * 4 + wv;
  size_t rb = row * 512;
  float v[8];
  float s = 0.f;
#pragma unroll
  for (int j = 0; j < 8; ++j) {
    size_t ix = rb + ln + j * 64;
    v[j] = ao[ix] * gate[ix] + skip[ix];
    s += v[j];
  }
#pragma unroll
  for (int off = 32; off; off >>= 1) s += __shfl_xor(s, off);
  float mu = s * (1.f / 512.f);
  float vs = 0.f;
#pragma unroll
  for (int j = 0; j < 8; ++j) { float d = v[j] - mu; vs += d * d; }
#pragma unroll
  for (int off = 32; off; off >>= 1) vs += __shfl_xor(vs, off);
  float rs = rsqrtf(vs * (1.f / 512.f) + 1e-6f);
#pragma unroll
  for (int j = 0; j < 8; ++j) {
    int cc = ln + j * 64;
    out[rb + cc] = (v[j] - mu) * rs * sc[cc] + bi[cc];
  }
}

// ---------------------------------------------------------------------------
// attention: one wg per (b, head); 512 threads = 1 query each; K/V in LDS.
__global__ __launch_bounds__(512) void attn_kernel(const float* __restrict__ qkv,
                                                   u16* __restrict__ ctx) {
  __shared__ float4 kL[512][2];
  __shared__ float4 vL[512][2];
  int tid = threadIdx.x;
  int b = blockIdx.x >> 3, hd = blockIdx.x & 7;
  size_t base = ((size_t)b * 512 + tid) * 192;
  kL[tid][0] = *(const float4*)(qkv + base + 64 + hd * 8);
  kL[tid][1] = *(const float4*)(qkv + base + 64 + hd * 8 + 4);
  vL[tid][0] = *(const float4*)(qkv + base + 128 + hd * 8);
  vL[tid][1] = *(const float4*)(qkv + base + 128 + hd * 8 + 4);
  float4 qa = *(const float4*)(qkv + base + hd * 8);
  float4 qb = *(const float4*)(qkv + base + hd * 8 + 4);
  const float scl = 0.35355339059327373f;  // 1/sqrt(8)
  float q0 = qa.x * scl, q1 = qa.y * scl, q2 = qa.z * scl, q3 = qa.w * scl;
  float q4 = qb.x * scl, q5 = qb.y * scl, q6 = qb.z * scl, q7 = qb.w * scl;
  __syncthreads();
  float m = -1e30f, l = 0.f;
  float a0 = 0, a1 = 0, a2 = 0, a3 = 0, a4 = 0, a5 = 0, a6 = 0, a7 = 0;
  for (int t2 = 0; t2 < 512; ++t2) {
    float4 ka = kL[t2][0], kb = kL[t2][1];
    float s = q0 * ka.x + q1 * ka.y + q2 * ka.z + q3 * ka.w +
              q4 * kb.x + q5 * kb.y + q6 * kb.z + q7 * kb.w;
    float nm = fmaxf(m, s);
    float cor = __expf(m - nm);
    float e = __expf(s - nm);
    float4 va = vL[t2][0], vb = vL[t2][1];
    l = l * cor + e;
    a0 = a0 * cor + e * va.x; a1 = a1 * cor + e * va.y;
    a2 = a2 * cor + e * va.z; a3 = a3 * cor + e * va.w;
    a4 = a4 * cor + e * vb.x; a5 = a5 * cor + e * vb.y;
    a6 = a6 * cor + e * vb.z; a7 = a7 * cor + e * vb.w;
    m = nm;
  }
  float inv = 1.f / l;
  short8 o;
  o[0] = (short)f2bf(a0 * inv); o[1] = (short)f2bf(a1 * inv);
  o[2] = (short)f2bf(a2 * inv); o[3] = (short)f2bf(a3 * inv);
  o[4] = (short)f2bf(a4 * inv); o[5] = (short)f2bf(a5 * inv);
  o[6] = (short)f2bf(a6 * inv); o[7] = (short)f2bf(a7 * inv);
  *(short8*)(ctx + ((size_t)b * 512 + tid) * 64 + hd * 8) = o;
}

// ---------------------------------------------------------------------------
extern "C" void kernel_launch(void* const* d_in, const int* in_sizes, int n_in,
                              void* d_out, int out_size, void* d_ws, size_t ws_size,
                              hipStream_t stream) {
  (void)in_sizes; (void)n_in; (void)out_size; (void)ws_size;
  const float* x    = (const float*)d_in[0];
  const float* Wx   = (const float*)d_in[1];
  const float* Wh   = (const float*)d_in[2];
  const float* bls  = (const float*)d_in[3];
  const float* ln1s = (const float*)d_in[4];
  const float* ln1b = (const float*)d_in[5];
  const float* Wq   = (const float*)d_in[6];
  const float* bq   = (const float*)d_in[7];
  const float* Wk   = (const float*)d_in[8];
  const float* bk   = (const float*)d_in[9];
  const float* Wv   = (const float*)d_in[10];
  const float* bv   = (const float*)d_in[11];
  const float* Wo   = (const float*)d_in[12];
  const float* bo   = (const float*)d_in[13];
  const float* Wg   = (const float*)d_in[14];
  const float* bg   = (const float*)d_in[15];
  const float* ln2s = (const float*)d_in[16];
  const float* ln2b = (const float*)d_in[17];
  float* out = (float*)d_out;

  char* p = (char*)d_ws;
  auto alloc = [&](size_t bytes) -> char* {
    char* r = p;
    p += (bytes + 255) & ~(size_t)255;
    return r;
  };
  int* flags    = (int*)alloc(512 * 4);
  unsigned int* h_buf = (unsigned int*)alloc(16 * 256 * 4);
  u16* x_bf     = (u16*)alloc((size_t)8192 * 512 * 2);
  u16* Wx_bf    = (u16*)alloc((size_t)512 * 2048 * 2);
  u16* Wqkv_bf  = (u16*)alloc((size_t)512 * 192 * 2);
  float* bqkv   = (float*)alloc(192 * 4);
  u16* Wg_bf    = (u16*)alloc((size_t)512 * 512 * 2);
  u16* Wo_bf    = (u16*)alloc((size_t)64 * 512 * 2);
  u16* xg_bf    = (u16*)alloc((size_t)8192 * 2048 * 2);
  float* hs     = (float*)alloc((size_t)8192 * 512 * 4);
  float* hF     = (float*)alloc((size_t)8192 * 512 * 4);
  u16* hB       = (u16*)alloc((size_t)8192 * 512 * 2);
  float* qkvb   = (float*)alloc((size_t)8192 * 192 * 4);
  float* gatep  = (float*)alloc((size_t)8192 * 512 * 4);
  u16* ctx      = (u16*)alloc((size_t)8192 * 64 * 2);
  float* ao     = (float*)alloc((size_t)8192 * 512 * 4);

  hipMemsetAsync(flags, 0, 512 * 4, stream);
  f2bf_kernel<<<16384, 256, 0, stream>>>(x, x_bf, 8192 * 512);
  f2bf_kernel<<<4096, 256, 0, stream>>>(Wx, Wx_bf, 512 * 2048);
  f2bf_kernel<<<1024, 256, 0, stream>>>(Wg, Wg_bf, 512 * 512);
  f2bf_kernel<<<128, 256, 0, stream>>>(Wo, Wo_bf, 64 * 512);
  pack_qkv_kernel<<<384, 256, 0, stream>>>(Wq, Wk, Wv, bq, bk, bv, Wqkv_bf, bqkv);

  // xg = x @ Wx + b  -> bf16 [8192,2048]
  gemm_bf16<<<dim3(128, 32), 256, 0, stream>>>(x_bf, Wx_bf, bls, nullptr, xg_bf,
                                               8192, 2048, 512, 0);
  // LSTM scan -> hs fp32 [8192,512]
  lstm_kernel<<<64, 256, 0, stream>>>(Wh, xg_bf, hs, h_buf, flags);
  // h = LN(hs)+x  -> hF fp32, hB bf16
  ln1_kernel<<<2048, 256, 0, stream>>>(hs, x, ln1s, ln1b, hF, hB);
  // qkv = h @ [Wq|Wk|Wv] + b  -> fp32 [8192,192]
  gemm_bf16<<<dim3(128, 3), 256, 0, stream>>>(hB, Wqkv_bf, bqkv, qkvb, nullptr,
                                              8192, 192, 512, 0);
  // gate = sigmoid(h @ Wg + bg)  -> fp32 [8192,512]
  gemm_bf16<<<dim3(128, 8), 256, 0, stream>>>(hB, Wg_bf, bg, gatep, nullptr,
                                              8192, 512, 512, 1);
  // attention -> ctx bf16 [8192,64]
  attn_kernel<<<128, 512, 0, stream>>>(qkvb, ctx);
  // attn_out = ctx @ Wo + bo -> fp32 [8192,512]
  gemm_bf16<<<dim3(128, 8), 256, 0, stream>>>(ctx, Wo_bf, bo, ao, nullptr,
                                              8192, 512, 64, 0);
  // out = LN(ao*gate + h)
  ln2_kernel<<<2048, 256, 0, stream>>>(ao, gatep, hF, ln2s, ln2b, out);
}